// Round 9
// baseline (161.054 us; speedup 1.0000x reference)
//
#include <hip/hip_runtime.h>

// Problem constants
#define BB 8
#define QQ 128
#define KK 1024
#define DD 256
#define HH 256

// scoreav split-K: 32 chunks of 32 k
#define KSP 32
#define KCH 32

// proj D-split
#define DQN 4
#define RTOT (BB * QQ + BB * KK)          // 9216 rows
#define PSTRIDE ((size_t)RTOT * HH)       // 2359296 floats per D-quarter buffer

#define TWO_LOG2E     2.8853900817779268f
#define NEG_TWO_LOG2E -2.8853900817779268f

// ---------------------------------------------------------------------------
// K1: Q+K projection, D-SPLIT into quarters (no exp2 here; combine happens in
// scoreav staging). Block = (row-tile 64, h-tile 128, d-quarter 64).
//   pp[dq][r][h] = TWO_LOG2E * sum_{d in quarter} A[r][d]*W[h][d]
// Grid 144 x 2 x 4 = 1152, ~700 live after mask skip = 2.7 blocks/CU
// (R8: 1.4/CU -> ds_read latency half-exposed, 26 us vs 13 us floor).
// Thread = 4r x 8h: rho = 12 b128 / 128 MAC.
// ---------------------------------------------------------------------------
__global__ __launch_bounds__(256) void proj_kernel(const float* __restrict__ queries,
                                                   const float* __restrict__ keys,
                                                   const float* __restrict__ Wq,
                                                   const float* __restrict__ Wk,
                                                   const int* __restrict__ vlen,
                                                   float* __restrict__ pp) {
    const int r0 = blockIdx.x * 64;
    const bool isQ = (r0 < BB * QQ);
    if (!isQ) {
        const int kb = (r0 - BB * QQ) >> 6;
        const int b  = kb >> 4;
        const int k0 = (kb & 15) << 6;
        if (k0 >= vlen[b]) return;   // masked key block (coverage >= scoreav reads)
    }

    __shared__ float As[64][68];     // pad 68: <=2-way banks
    __shared__ float Ws[128][68];
    const int t  = threadIdx.x;
    const int tr = t & 15;           // rows {tr+16i, i<4}
    const int th = t >> 4;           // hs   {th+16j, j<8}
    const int h0 = blockIdx.y * 128;
    const int dc = blockIdx.z * 64;  // d-quarter base
    const float* A = isQ ? (queries + (size_t)r0 * DD)
                         : (keys + (size_t)(r0 - BB * QQ) * DD);
    const float* W = isQ ? Wq : Wk;

#pragma unroll
    for (int i = 0; i < 4; ++i) {    // A: 1024 float4 slots
        int fi = t + 256 * i; int row = fi >> 4; int c4 = (fi & 15) << 2;
        *(float4*)&As[row][c4] = *(const float4*)&A[(size_t)row * DD + dc + c4];
    }
#pragma unroll
    for (int i = 0; i < 8; ++i) {    // W: 2048 float4 slots
        int fi = t + 256 * i; int row = fi >> 4; int c4 = (fi & 15) << 2;
        *(float4*)&Ws[row][c4] = *(const float4*)&W[(size_t)(h0 + row) * DD + dc + c4];
    }
    __syncthreads();

    float acc[4][8] = {};
#pragma unroll 2
    for (int dd = 0; dd < 64; dd += 4) {
        float4 a4[4], w4[8];
#pragma unroll
        for (int i = 0; i < 4; ++i) a4[i] = *(float4*)&As[tr + 16 * i][dd];
#pragma unroll
        for (int j = 0; j < 8; ++j) w4[j] = *(float4*)&Ws[th + 16 * j][dd];
#pragma unroll
        for (int ri = 0; ri < 4; ++ri)
#pragma unroll
            for (int hi = 0; hi < 8; ++hi) {
                acc[ri][hi] += a4[ri].x * w4[hi].x + a4[ri].y * w4[hi].y +
                               a4[ri].z * w4[hi].z + a4[ri].w * w4[hi].w;
            }
    }

    float* out = pp + (size_t)blockIdx.z * PSTRIDE;
#pragma unroll
    for (int ri = 0; ri < 4; ++ri)
#pragma unroll
        for (int hi = 0; hi < 8; ++hi) {
            out[(size_t)(r0 + tr + 16 * ri) * HH + h0 + th + 16 * hi] =
                TWO_LOG2E * acc[ri][hi];
        }
}

// ---------------------------------------------------------------------------
// K2: FUSED score + A*V, 512 threads, h-SLICED over 8 waves.
// Work compaction: dense items (b, ksb<nch, qtile<4); max 1024 blocks
// (R8 under-launched 512 -- passed by luck of the seed; fixed here).
// Score: wave w owns 32 h; thread register-tile 4q x 4k -> 2 B LDS/term
// (floor ~5 us vs 10 us at 2q x 2k). Staging combines the 4 proj D-quarters
// + exp2 inline. Wave partial accs -> LDS tree (red aliased over dead
// staging buffer, bank-safe q*33+k layout) -> masked exp2 -> pT -> av.
// ---------------------------------------------------------------------------
__global__ __launch_bounds__(512) void scoreav_kernel(const float* __restrict__ pp,
                                                      const float* __restrict__ wv,
                                                      const int* __restrict__ vlen,
                                                      const float* __restrict__ V,
                                                      float* __restrict__ partial,
                                                      float* __restrict__ psum) {
    // ---- work-item compaction ----
    int id = blockIdx.x;
    int b = 0;
    bool found = false;
#pragma unroll
    for (int bb = 0; bb < BB; ++bb) {
        if (!found) {
            int v = vlen[bb];
            int cnt = ((v == 0) ? KSP : ((v + KCH - 1) / KCH)) * 4;
            if (id < cnt) { b = bb; found = true; }
            else id -= cnt;
        }
    }
    if (!found) return;
    const int ksb = id >> 2;
    const int q0  = (id & 3) * 32;
    const int k0  = ksb * KCH;
    const int vl  = vlen[b];

    __shared__ float st[2][32][136];   // [0]=q rows, [1]=k rows; h-half staged
    __shared__ float pT[32][36];       // [k][q]
    float* red = &st[0][0][0];         // alias: red[w*1056 + q*33 + k], 8448 floats

    const int t = threadIdx.x;
    const int w = t >> 6;              // wave 0..7
    const int l = t & 63;

    float acc[4][4] = {};

    if (vl > 0) {
        const int ql = l & 7;          // q's = 4*ql + i
        const int kl = l >> 3;         // k's = 4*kl + j
#pragma unroll
        for (int hp = 0; hp < 2; ++hp) {           // h-half 128
            const int hb = hp * 128;
            // stage 2048 f4 (q 32x128 + k 32x128), 4/thread, 4-quarter combine
#pragma unroll
            for (int i = 0; i < 4; ++i) {
                int fi  = t + 512 * i;             // 0..2047
                int row = fi >> 5;                 // 0..63
                int c4  = (fi & 31) << 2;          // 0..124
                size_t gr = (row < 32) ? (size_t)(b * QQ + q0 + row)
                                       : (size_t)(BB * QQ + b * KK + k0 + row - 32);
                const float* base = pp + gr * HH + hb + c4;
                float4 v0 = *(const float4*)base;
                float4 v1 = *(const float4*)(base + PSTRIDE);
                float4 v2 = *(const float4*)(base + 2 * PSTRIDE);
                float4 v3 = *(const float4*)(base + 3 * PSTRIDE);
                float4 s;
                s.x = __builtin_amdgcn_exp2f(v0.x + v1.x + v2.x + v3.x);
                s.y = __builtin_amdgcn_exp2f(v0.y + v1.y + v2.y + v3.y);
                s.z = __builtin_amdgcn_exp2f(v0.z + v1.z + v2.z + v3.z);
                s.w = __builtin_amdgcn_exp2f(v0.w + v1.w + v2.w + v3.w);
                *(float4*)&st[row >> 5][row & 31][c4] = s;
            }
            __syncthreads();

            const int hw = 16 * w;                 // wave's 16-h window (local col)
#pragma unroll
            for (int hh = 0; hh < 16; hh += 4) {
                const float4 w4 = *(const float4*)&wv[hb + hw + hh];  // scalar
                const float* wa = (const float*)&w4;
                float4 q4[4], k4[4];
#pragma unroll
                for (int i = 0; i < 4; ++i) q4[i] = *(float4*)&st[0][4 * ql + i][hw + hh];
#pragma unroll
                for (int j = 0; j < 4; ++j) k4[j] = *(float4*)&st[1][4 * kl + j][hw + hh];
#pragma unroll
                for (int i = 0; i < 4; ++i) {
                    const float* qa = (const float*)&q4[i];
#pragma unroll
                    for (int j = 0; j < 4; ++j) {
                        const float* ka = (const float*)&k4[j];
#pragma unroll
                        for (int c = 0; c < 4; ++c) {
                            float d = __builtin_fmaf(qa[c], ka[c], 1.0f);
                            acc[i][j] += wa[c] * __builtin_amdgcn_rcpf(d);
                        }
                    }
                }
            }
            __syncthreads();   // staging buffer reuse (and red alias) safety
        }

        // write wave-partial accs into red (aliased over dead staging LDS)
#pragma unroll
        for (int i = 0; i < 4; ++i)
#pragma unroll
            for (int j = 0; j < 4; ++j)
                red[w * 1056 + (4 * ql + i) * 33 + (4 * kl + j)] = acc[i][j];
    }
    __syncthreads();

    // ---- combine across waves, masked exp2, pT + psum ----
    float pvv[2];
#pragma unroll
    for (int u = 0; u < 2; ++u) {
        int n = t + 512 * u;               // 0..1023
        int q = n >> 5, k = n & 31;
        float s = 0.f;
        if (vl > 0) {
#pragma unroll
            for (int ww = 0; ww < 8; ++ww) s += red[ww * 1056 + q * 33 + k];
        }
        int kg = k0 + k;
        float pv;
        if (vl == 0) pv = 1.0f;            // uniform row (ref behavior)
        else pv = (kg < vl) ? __builtin_amdgcn_exp2f(NEG_TWO_LOG2E * s) : 0.0f;
        pT[k][q] = pv;
        pvv[u] = pv;
    }
    // psum: reduce over the 32 lanes sharing q (k = l&31)
    float s0 = pvv[0], s1 = pvv[1];
#pragma unroll
    for (int off = 1; off < 32; off <<= 1) {
        s0 += __shfl_xor(s0, off);
        s1 += __shfl_xor(s1, off);
    }
    if ((l & 31) == 0) {
        int q1 = 2 * w + (l >> 5);         // q of pvv[0]; pvv[1] is q1+16
        psum[((size_t)ksb * BB + b) * QQ + q0 + q1]      = s0;
        psum[((size_t)ksb * BB + b) * QQ + q0 + q1 + 16] = s1;
    }
    __syncthreads();

    // ---- av phase: thread = (4d x 4q), 8 q-groups over 8 waves ----
    const float* VB = V + ((size_t)b * KK + k0) * DD;
    const int d4 = (t & 63) << 2;
    const int qg = (t >> 6) << 2;          // 0,4,...,28
    float4 a4[4] = {};
#pragma unroll 4
    for (int k = 0; k < KCH; ++k) {
        float4 v4 = *(const float4*)&VB[(size_t)k * DD + d4];   // coalesced
        float4 p4 = *(float4*)&pT[k][qg];                       // broadcast
        a4[0].x += p4.x * v4.x; a4[0].y += p4.x * v4.y; a4[0].z += p4.x * v4.z; a4[0].w += p4.x * v4.w;
        a4[1].x += p4.y * v4.x; a4[1].y += p4.y * v4.y; a4[1].z += p4.y * v4.z; a4[1].w += p4.y * v4.w;
        a4[2].x += p4.z * v4.x; a4[2].y += p4.z * v4.y; a4[2].z += p4.z * v4.z; a4[2].w += p4.z * v4.w;
        a4[3].x += p4.w * v4.x; a4[3].y += p4.w * v4.y; a4[3].z += p4.w * v4.z; a4[3].w += p4.w * v4.w;
    }
#pragma unroll
    for (int qi = 0; qi < 4; ++qi) {
        int q = q0 + qg + qi;
        *(float4*)&partial[(((size_t)ksb * BB + b) * QQ + q) * DD + d4] = a4[qi];
    }
}

// ---------------------------------------------------------------------------
// K3: mask-aware reduce over the nch(b) live chunks + softmax normalization.
// ---------------------------------------------------------------------------
__global__ __launch_bounds__(256) void av_reduce(const float* __restrict__ partial,
                                                 const float* __restrict__ psum,
                                                 const int* __restrict__ vlen,
                                                 float* __restrict__ out) {
    const int i  = blockIdx.x * 256 + threadIdx.x;   // float4 index, 65536 total
    const int bq = i >> 6;                           // b*QQ + q
    const int b  = bq >> 7;
    const int vl = vlen[b];
    const int nch = (vl == 0) ? KSP : ((vl + KCH - 1) / KCH);

    float S = 0.f;
    for (int ks = 0; ks < nch; ++ks) S += psum[(size_t)ks * (BB * QQ) + bq];

    const float4* p4 = (const float4*)partial;
    const int stride4 = BB * QQ * DD / 4;            // 65536
    float4 s = {0.f, 0.f, 0.f, 0.f};
    for (int ks = 0; ks < nch; ++ks) {
        float4 x = p4[(size_t)ks * stride4 + i];
        s.x += x.x; s.y += x.y; s.z += x.z; s.w += x.w;
    }
    const float inv = 1.0f / S;   // S>0 always: p>=8e-12 unmasked, vl==0 -> p=1
    s.x *= inv; s.y *= inv; s.z *= inv; s.w *= inv;
    ((float4*)out)[i] = s;
}

// ---------------------------------------------------------------------------
extern "C" void kernel_launch(void* const* d_in, const int* in_sizes, int n_in,
                              void* d_out, int out_size, void* d_ws, size_t ws_size,
                              hipStream_t stream) {
    const float* queries = (const float*)d_in[0];   // [B,Q,D]
    const float* keys    = (const float*)d_in[1];   // [B,K,D]
    const float* values  = (const float*)d_in[2];   // [B,K,D]
    const float* W_q     = (const float*)d_in[3];   // [H,D]
    const float* W_k     = (const float*)d_in[4];   // [H,D]
    const float* w_v     = (const float*)d_in[5];   // [H]
    const int*   vlen    = (const int*)d_in[6];     // [B]
    float* out = (float*)d_out;

    float* ws      = (float*)d_ws;
    float* pproj   = ws;                                   // DQN*PSTRIDE = 37.7 MB
    float* psum    = pproj + (size_t)DQN * PSTRIDE;        // KSP*B*Q = 32768
    float* partial = psum + (size_t)KSP * BB * QQ;         // KSP*B*Q*D = 33.5 MB
    // no aliasing: scoreav reads pproj while writing partial. ~71 MB of ws.

    // D-split projection (no exp2), masked key blocks skipped
    proj_kernel<<<dim3(RTOT / 64, HH / 128, DQN), 256, 0, stream>>>(
        queries, keys, W_q, W_k, vlen, pproj);

    // Fused score + A*V, h-sliced 512-thread blocks, work-compacted.
    // Max items = KSP*4*BB = 1024 (launch the full max; R8's 512 was a bug).
    scoreav_kernel<<<dim3(KSP * 4 * BB, 1, 1), 512, 0, stream>>>(
        pproj, w_v, vlen, values, partial, psum);

    // Mask-aware reduce + softmax normalization
    av_reduce<<<dim3(BB * QQ * DD / 4 / 256, 1, 1), 256, 0, stream>>>(
        partial, psum, vlen, out);
}

// Round 10
// 161.014 us; speedup vs baseline: 1.0003x; 1.0003x over previous
//
#include <hip/hip_runtime.h>

// Problem constants
#define BB 8
#define QQ 128
#define KK 1024
#define DD 256
#define HH 256

// scoreav split-K: 32 chunks of 32 k
#define KSP 32
#define KCH 32

#define TWO_LOG2E     2.8853900817779268f
#define NEG_TWO_LOG2E -2.8853900817779268f

// ---------------------------------------------------------------------------
// K1: fused Q+K projection with exp2 epilogue (R8 version, known good).
//   eproj[r][h] = exp2( TWO_LOG2E * sum_d A[r][d]*W[h][d] )   (9.4 MB, L3-hot)
// MASK SKIP: key blocks fully >= vl[b] -> early out. Coverage ceil(vl/64)*64
// >= scoreav's max read ceil(vl/32)*32, so no poison is ever read.
// ---------------------------------------------------------------------------
__global__ __launch_bounds__(256) void proj_kernel(const float* __restrict__ queries,
                                                   const float* __restrict__ keys,
                                                   const float* __restrict__ Wq,
                                                   const float* __restrict__ Wk,
                                                   const int* __restrict__ vlen,
                                                   float* __restrict__ eproj) {
    const int r0 = blockIdx.x * 64;
    const bool isQ = (r0 < BB * QQ);
    if (!isQ) {
        const int kb = (r0 - BB * QQ) >> 6;
        const int b  = kb >> 4;
        const int k0 = (kb & 15) << 6;
        if (k0 >= vlen[b]) return;               // fully masked (vl==0 too)
    }

    __shared__ float As[64][68];  // pad 68: <=2-way banks (free)
    __shared__ float Ws[64][68];
    const int t  = threadIdx.x;
    const int tr = t & 15;
    const int th = t >> 4;
    const int h0 = blockIdx.y * 64;
    const float* A = isQ ? (queries + (size_t)r0 * DD)
                         : (keys + (size_t)(r0 - BB * QQ) * DD);
    const float* W = isQ ? Wq : Wk;

    float acc[4][4] = {};

    for (int dc = 0; dc < DD; dc += 64) {
#pragma unroll
        for (int i = 0; i < 4; ++i) {
            int fi  = t + 256 * i;
            int row = fi >> 4;
            int c4  = (fi & 15) << 2;
            *(float4*)&As[row][c4] = *(const float4*)&A[(size_t)row * DD + dc + c4];
            *(float4*)&Ws[row][c4] = *(const float4*)&W[(size_t)(h0 + row) * DD + dc + c4];
        }
        __syncthreads();
#pragma unroll 4
        for (int dd = 0; dd < 64; dd += 4) {
            float4 a4[4], w4[4];
#pragma unroll
            for (int i = 0; i < 4; ++i) a4[i] = *(float4*)&As[tr + 16 * i][dd];
#pragma unroll
            for (int i = 0; i < 4; ++i) w4[i] = *(float4*)&Ws[th + 16 * i][dd];
#pragma unroll
            for (int ri = 0; ri < 4; ++ri)
#pragma unroll
                for (int hi = 0; hi < 4; ++hi) {
                    acc[ri][hi] += a4[ri].x * w4[hi].x + a4[ri].y * w4[hi].y +
                                   a4[ri].z * w4[hi].z + a4[ri].w * w4[hi].w;
                }
        }
        __syncthreads();
    }
#pragma unroll
    for (int ri = 0; ri < 4; ++ri)
#pragma unroll
        for (int hi = 0; hi < 4; ++hi) {
            eproj[(size_t)(r0 + tr + 16 * ri) * HH + h0 + th + 16 * hi] =
                __builtin_amdgcn_exp2f(TWO_LOG2E * acc[ri][hi]);
        }
}

// ---------------------------------------------------------------------------
// K2: FUSED score + A*V, work-compacted, NO q/k LDS staging.
// Score fragments are broadcast-heavy (one q-f4 address per 16 lanes; a
// wave-quad touches ~640 B unique, ~16 KB/hc window -> L1-resident) so they
// are read DIRECTLY from eproj: no staging writes, no barriers in the
// h-loop, LDS = pT only (4.6 KB). Unroll-4 -> 16 independent loads in
// flight hide L2 latency. Trans pipe (1 rcp/term) is the only binding pipe.
// Dense items (b, ksb<nch, qtile<4); full max 1024 blocks launched
// (R8 under-launched 512 and passed by seed luck).
// ---------------------------------------------------------------------------
__global__ __launch_bounds__(256) void scoreav_kernel(const float* __restrict__ eproj,
                                                      const float* __restrict__ wv,
                                                      const int* __restrict__ vlen,
                                                      const float* __restrict__ V,
                                                      float* __restrict__ partial,
                                                      float* __restrict__ psum) {
    // ---- work-item compaction (uniform scalar scan) ----
    int id = blockIdx.x;
    int b = 0;
    bool found = false;
#pragma unroll
    for (int bb = 0; bb < BB; ++bb) {
        if (!found) {
            int v = vlen[bb];
            int cnt = ((v == 0) ? KSP : ((v + KCH - 1) / KCH)) * 4;
            if (id < cnt) { b = bb; found = true; }
            else id -= cnt;
        }
    }
    if (!found) return;
    const int ksb = id >> 2;
    const int q0  = (id & 3) * 32;
    const int k0  = ksb * KCH;
    const int vl  = vlen[b];

    __shared__ float pT[KCH][36];        // [k][q], only LDS in the kernel
    const int t  = threadIdx.x;
    const int tk = t & 15;               // k's = {tk, tk+16}
    const int tq = t >> 4;               // q's = {tq, tq+16}

    // ---- score phase: direct global fragment reads, zero barriers ----
    float acc[2][2] = {};
    if (vl > 0) {
        const float* qp0 = eproj + (size_t)(b * QQ + q0 + tq) * HH;
        const float* qp1 = eproj + (size_t)(b * QQ + q0 + tq + 16) * HH;
        const float* kp0 = eproj + (size_t)(BB * QQ + b * KK + k0 + tk) * HH;
        const float* kp1 = eproj + (size_t)(BB * QQ + b * KK + k0 + tk + 16) * HH;

#pragma unroll 4
        for (int hh = 0; hh < HH; hh += 4) {
            const float4 w4 = *(const float4*)&wv[hh];     // wave-uniform: s_load
            const float* wa = (const float*)&w4;
            float4 q40 = *(const float4*)&qp0[hh];         // broadcast-y L1 hits
            float4 q41 = *(const float4*)&qp1[hh];
            float4 k40 = *(const float4*)&kp0[hh];
            float4 k41 = *(const float4*)&kp1[hh];
            const float* qa0 = (const float*)&q40;
            const float* qa1 = (const float*)&q41;
            const float* ka0 = (const float*)&k40;
            const float* ka1 = (const float*)&k41;
#pragma unroll
            for (int c = 0; c < 4; ++c) {
                float d00 = __builtin_fmaf(qa0[c], ka0[c], 1.0f);
                float d01 = __builtin_fmaf(qa0[c], ka1[c], 1.0f);
                float d10 = __builtin_fmaf(qa1[c], ka0[c], 1.0f);
                float d11 = __builtin_fmaf(qa1[c], ka1[c], 1.0f);
                acc[0][0] += wa[c] * __builtin_amdgcn_rcpf(d00);
                acc[0][1] += wa[c] * __builtin_amdgcn_rcpf(d01);
                acc[1][0] += wa[c] * __builtin_amdgcn_rcpf(d10);
                acc[1][1] += wa[c] * __builtin_amdgcn_rcpf(d11);
            }
        }
    }

    // ---- epilogue: masked pv -> pT[k][q] (2-way banks); 16-lane row sums ----
    float sj[2] = {0.f, 0.f};
#pragma unroll
    for (int i = 0; i < 2; ++i)
#pragma unroll
        for (int j = 0; j < 2; ++j) {
            int kg = k0 + tk + 16 * j;
            float pv;
            if (vl == 0) pv = 1.0f;      // uniform row (ref behavior)
            else pv = (kg < vl) ? __builtin_amdgcn_exp2f(NEG_TWO_LOG2E * acc[i][j])
                                : 0.0f;
            pT[tk + 16 * j][tq + 16 * i] = pv;
            sj[i] += pv;
        }
#pragma unroll
    for (int off = 1; off < 16; off <<= 1) {
        sj[0] += __shfl_xor(sj[0], off);
        sj[1] += __shfl_xor(sj[1], off);
    }
    if (tk == 0) {
        psum[((size_t)ksb * BB + b) * QQ + q0 + tq]      = sj[0];
        psum[((size_t)ksb * BB + b) * QQ + q0 + tq + 16] = sj[1];
    }
    __syncthreads();

    // ---- av phase: thread = (4d x 8q) ----
    const float* VB = V + ((size_t)b * KK + k0) * DD;
    const int d4 = (t & 63) << 2;
    const int qh = (t >> 6) << 3;        // 0,8,16,24
    float4 acc4[8] = {};
#pragma unroll 4
    for (int k = 0; k < KCH; ++k) {
        float4 v4 = *(const float4*)&VB[(size_t)k * DD + d4];   // coalesced
        float4 p0 = *(float4*)&pT[k][qh];        // broadcast reads
        float4 p1 = *(float4*)&pT[k][qh + 4];
        acc4[0].x += p0.x * v4.x; acc4[0].y += p0.x * v4.y; acc4[0].z += p0.x * v4.z; acc4[0].w += p0.x * v4.w;
        acc4[1].x += p0.y * v4.x; acc4[1].y += p0.y * v4.y; acc4[1].z += p0.y * v4.z; acc4[1].w += p0.y * v4.w;
        acc4[2].x += p0.z * v4.x; acc4[2].y += p0.z * v4.y; acc4[2].z += p0.z * v4.z; acc4[2].w += p0.z * v4.w;
        acc4[3].x += p0.w * v4.x; acc4[3].y += p0.w * v4.y; acc4[3].z += p0.w * v4.z; acc4[3].w += p0.w * v4.w;
        acc4[4].x += p1.x * v4.x; acc4[4].y += p1.x * v4.y; acc4[4].z += p1.x * v4.z; acc4[4].w += p1.x * v4.w;
        acc4[5].x += p1.y * v4.x; acc4[5].y += p1.y * v4.y; acc4[5].z += p1.y * v4.z; acc4[5].w += p1.y * v4.w;
        acc4[6].x += p1.z * v4.x; acc4[6].y += p1.z * v4.y; acc4[6].z += p1.z * v4.z; acc4[6].w += p1.z * v4.w;
        acc4[7].x += p1.w * v4.x; acc4[7].y += p1.w * v4.y; acc4[7].z += p1.w * v4.z; acc4[7].w += p1.w * v4.w;
    }

#pragma unroll
    for (int qi = 0; qi < 8; ++qi) {
        int q = q0 + qh + qi;
        *(float4*)&partial[(((size_t)ksb * BB + b) * QQ + q) * DD + d4] = acc4[qi];
    }
}

// ---------------------------------------------------------------------------
// K3: mask-aware reduce over the nch(b) live chunks + softmax normalization.
// ---------------------------------------------------------------------------
__global__ __launch_bounds__(256) void av_reduce(const float* __restrict__ partial,
                                                 const float* __restrict__ psum,
                                                 const int* __restrict__ vlen,
                                                 float* __restrict__ out) {
    const int i  = blockIdx.x * 256 + threadIdx.x;   // float4 index, 65536 total
    const int bq = i >> 6;                           // b*QQ + q
    const int b  = bq >> 7;
    const int vl = vlen[b];
    const int nch = (vl == 0) ? KSP : ((vl + KCH - 1) / KCH);

    float S = 0.f;
    for (int ks = 0; ks < nch; ++ks) S += psum[(size_t)ks * (BB * QQ) + bq];

    const float4* p4 = (const float4*)partial;
    const int stride4 = BB * QQ * DD / 4;            // 65536
    float4 s = {0.f, 0.f, 0.f, 0.f};
    for (int ks = 0; ks < nch; ++ks) {
        float4 x = p4[(size_t)ks * stride4 + i];
        s.x += x.x; s.y += x.y; s.z += x.z; s.w += x.w;
    }
    const float inv = 1.0f / S;   // S>0 always: p>=8e-12 unmasked, vl==0 -> p=1
    s.x *= inv; s.y *= inv; s.z *= inv; s.w *= inv;
    ((float4*)out)[i] = s;
}

// ---------------------------------------------------------------------------
extern "C" void kernel_launch(void* const* d_in, const int* in_sizes, int n_in,
                              void* d_out, int out_size, void* d_ws, size_t ws_size,
                              hipStream_t stream) {
    const float* queries = (const float*)d_in[0];   // [B,Q,D]
    const float* keys    = (const float*)d_in[1];   // [B,K,D]
    const float* values  = (const float*)d_in[2];   // [B,K,D]
    const float* W_q     = (const float*)d_in[3];   // [H,D]
    const float* W_k     = (const float*)d_in[4];   // [H,D]
    const float* w_v     = (const float*)d_in[5];   // [H]
    const int*   vlen    = (const int*)d_in[6];     // [B]
    float* out = (float*)d_out;

    float* ws      = (float*)d_ws;
    float* eproj   = ws;                                        // 2359296 floats
    float* psum    = eproj + (size_t)(BB * QQ + BB * KK) * HH;  // KSP*B*Q = 32768
    float* partial = psum + (size_t)KSP * BB * QQ;              // 33.5 MB
    // no aliasing: scoreav reads eproj while writing partial. ~45 MB of ws.

    // Fused Q+K projection with exp2 epilogue, masked key blocks skipped
    proj_kernel<<<dim3((BB * QQ + BB * KK) / 64, HH / 64, 1), 256, 0, stream>>>(
        queries, keys, W_q, W_k, vlen, eproj);

    // Fused score + A*V, direct-L1 fragment reads, full 1024-item launch
    scoreav_kernel<<<dim3(KSP * 4 * BB, 1, 1), 256, 0, stream>>>(
        eproj, w_v, vlen, values, partial, psum);

    // Mask-aware reduce + softmax normalization
    av_reduce<<<dim3(BB * QQ * DD / 4 / 256, 1, 1), 256, 0, stream>>>(
        partial, psum, vlen, out);
}

// Round 11
// 149.263 us; speedup vs baseline: 1.0790x; 1.0787x over previous
//
#include <hip/hip_runtime.h>

// Problem constants
#define BB 8
#define QQ 128
#define KK 1024
#define DD 256
#define HH 256

// scoreav split-K: 32 chunks of 32 k
#define KSP 32
#define KCH 32

#define TWO_LOG2E     2.8853900817779268f
#define NEG_TWO_LOG2E -2.8853900817779268f

// ---------------------------------------------------------------------------
// K1: fused Q+K projection with exp2 epilogue. v2: W fragments read DIRECTLY
// from global (4 lines/wave-load, 16 KB tile L1-resident, reused 16 dd-steps
// x 4 waves) -> LDS demand halves (per-CU ceiling 21.5 -> ~11 us). A stays
// LDS-staged (its lane pattern would gather 16 lines from global).
// MASK SKIP: key blocks fully >= vl[b] -> early out.
// ---------------------------------------------------------------------------
__global__ __launch_bounds__(256) void proj_kernel(const float* __restrict__ queries,
                                                   const float* __restrict__ keys,
                                                   const float* __restrict__ Wq,
                                                   const float* __restrict__ Wk,
                                                   const int* __restrict__ vlen,
                                                   float* __restrict__ eproj) {
    const int r0 = blockIdx.x * 64;
    const bool isQ = (r0 < BB * QQ);
    if (!isQ) {
        const int kb = (r0 - BB * QQ) >> 6;
        const int b  = kb >> 4;
        const int k0 = (kb & 15) << 6;
        if (k0 >= vlen[b]) return;               // fully masked (vl==0 too)
    }

    __shared__ float As[64][68];  // pad 68: <=2-way banks (free)
    const int t  = threadIdx.x;
    const int tr = t & 15;
    const int th = t >> 4;
    const int h0 = blockIdx.y * 64;
    const float* A = isQ ? (queries + (size_t)r0 * DD)
                         : (keys + (size_t)(r0 - BB * QQ) * DD);
    const float* W = isQ ? Wq : Wk;

    float acc[4][4] = {};

    for (int dc = 0; dc < DD; dc += 64) {
#pragma unroll
        for (int i = 0; i < 4; ++i) {
            int fi  = t + 256 * i;
            int row = fi >> 4;
            int c4  = (fi & 15) << 2;
            *(float4*)&As[row][c4] = *(const float4*)&A[(size_t)row * DD + dc + c4];
        }
        __syncthreads();
#pragma unroll 4
        for (int dd = 0; dd < 64; dd += 4) {
            float4 a4[4], w4[4];
#pragma unroll
            for (int i = 0; i < 4; ++i) a4[i] = *(float4*)&As[tr + 16 * i][dd];
#pragma unroll
            for (int i = 0; i < 4; ++i)
                w4[i] = *(const float4*)&W[(size_t)(h0 + th + 16 * i) * DD + dc + dd];
#pragma unroll
            for (int ri = 0; ri < 4; ++ri)
#pragma unroll
                for (int hi = 0; hi < 4; ++hi) {
                    acc[ri][hi] += a4[ri].x * w4[hi].x + a4[ri].y * w4[hi].y +
                                   a4[ri].z * w4[hi].z + a4[ri].w * w4[hi].w;
                }
        }
        __syncthreads();
    }
#pragma unroll
    for (int ri = 0; ri < 4; ++ri)
#pragma unroll
        for (int hi = 0; hi < 4; ++hi) {
            eproj[(size_t)(r0 + tr + 16 * ri) * HH + h0 + th + 16 * hi] =
                __builtin_amdgcn_exp2f(TWO_LOG2E * acc[ri][hi]);
        }
}

// ---------------------------------------------------------------------------
// K2: FUSED score + A*V v3 — h-sliced 8 waves, one-shot staging.
// 512 threads; wave w owns h in [32w, 32w+32); thread = 4q x 4k over the
// 32x32 tile. q+k rows staged ONCE (64 KB, coalesced 1KB/wave loads), then
// the h-loop runs with ZERO barriers (R8 had 8) and conflict-free fragment
// reads (rows {x+8i}, stride 260 = 4 mod 32 -> 8 lanes hit 8 distinct banks).
// Wave partials -> red (aliased over dead staging) -> masked exp2 -> pT ->
// av (8 waves, 4d x 4q). ~4 waves/SIMD where live (vs 2.1 in R8/R10 -- the
// structure-independent ~40-49us was wave starvation).
// ---------------------------------------------------------------------------
__global__ __launch_bounds__(512, 4) void scoreav_kernel(const float* __restrict__ eproj,
                                                         const float* __restrict__ wv,
                                                         const int* __restrict__ vlen,
                                                         const float* __restrict__ V,
                                                         float* __restrict__ partial,
                                                         float* __restrict__ psum) {
    // ---- work-item compaction (uniform scalar scan) ----
    int id = blockIdx.x;
    int b = 0;
    bool found = false;
#pragma unroll
    for (int bb = 0; bb < BB; ++bb) {
        if (!found) {
            int v = vlen[bb];
            int cnt = ((v == 0) ? KSP : ((v + KCH - 1) / KCH)) * 4;
            if (id < cnt) { b = bb; found = true; }
            else id -= cnt;
        }
    }
    if (!found) return;
    const int ksb = id >> 2;
    const int q0  = (id & 3) * 32;
    const int k0  = ksb * KCH;
    const int vl  = vlen[b];

    __shared__ float st[2][32][260];   // [0]=q rows, [1]=k rows; all 256 h. 66.6 KB
    __shared__ float pT[KCH][36];      // [k][q]
    float* red = &st[0][0][0];         // alias: red[w*1056 + q*33 + k] (33.8 KB)

    const int t = threadIdx.x;
    const int w = t >> 6;              // wave 0..7
    const int l = t & 63;
    const int ql = l & 7;              // q rows {ql + 8i}
    const int kl = l >> 3;             // k rows {kl + 8j}

    float acc[4][4] = {};

    if (vl > 0) {
        // stage q (32 rows) + k (32 rows) x 256 h: 4096 f4, 8 per thread;
        // each wave reads one contiguous 1 KB row per load (fully coalesced).
#pragma unroll
        for (int i = 0; i < 8; ++i) {
            int fi  = t + 512 * i;             // 0..4095
            int row = fi >> 6;                 // 0..63
            int c4  = (fi & 63) << 2;          // 0..252
            size_t gr = (row < 32) ? (size_t)(b * QQ + q0 + row)
                                   : (size_t)(BB * QQ + b * KK + k0 + row - 32);
            *(float4*)&st[row >> 5][row & 31][c4] =
                *(const float4*)&eproj[gr * HH + c4];
        }
        __syncthreads();

        const int hw = 32 * w;                 // wave's h window
#pragma unroll
        for (int hh = 0; hh < 32; hh += 4) {
            const float4 w4 = *(const float4*)&wv[hw + hh];   // wave-uniform
            const float* wa = (const float*)&w4;
            float4 q4[4], k4[4];
#pragma unroll
            for (int i = 0; i < 4; ++i) q4[i] = *(float4*)&st[0][ql + 8 * i][hw + hh];
#pragma unroll
            for (int j = 0; j < 4; ++j) k4[j] = *(float4*)&st[1][kl + 8 * j][hw + hh];
#pragma unroll
            for (int i = 0; i < 4; ++i) {
                const float* qa = (const float*)&q4[i];
#pragma unroll
                for (int j = 0; j < 4; ++j) {
                    const float* ka = (const float*)&k4[j];
#pragma unroll
                    for (int c = 0; c < 4; ++c) {
                        float d = __builtin_fmaf(qa[c], ka[c], 1.0f);
                        acc[i][j] += wa[c] * __builtin_amdgcn_rcpf(d);
                    }
                }
            }
        }
        __syncthreads();   // staging dead; red may now overwrite it

        // wave-partial accs -> red
#pragma unroll
        for (int i = 0; i < 4; ++i)
#pragma unroll
            for (int j = 0; j < 4; ++j)
                red[w * 1056 + (ql + 8 * i) * 33 + (kl + 8 * j)] = acc[i][j];
    }
    __syncthreads();

    // ---- combine across waves, masked exp2, pT + psum ----
    float pvv[2];
#pragma unroll
    for (int u = 0; u < 2; ++u) {
        int n = t + 512 * u;               // 0..1023
        int q = n >> 5, k = n & 31;
        float s = 0.f;
        if (vl > 0) {
#pragma unroll
            for (int ww = 0; ww < 8; ++ww) s += red[ww * 1056 + q * 33 + k];
        }
        int kg = k0 + k;
        float pv;
        if (vl == 0) pv = 1.0f;            // uniform row (ref behavior)
        else pv = (kg < vl) ? __builtin_amdgcn_exp2f(NEG_TWO_LOG2E * s) : 0.0f;
        pT[k][q] = pv;
        pvv[u] = pv;
    }
    // psum: lanes 0-31 / 32-63 of each wave share a q; reduce within halves
    float s0 = pvv[0], s1 = pvv[1];
#pragma unroll
    for (int off = 1; off < 32; off <<= 1) {
        s0 += __shfl_xor(s0, off);
        s1 += __shfl_xor(s1, off);
    }
    if ((l & 31) == 0) {
        int qa = 2 * w + (l >> 5);         // q for u=0; u=1 is qa+16
        psum[((size_t)ksb * BB + b) * QQ + q0 + qa]      = s0;
        psum[((size_t)ksb * BB + b) * QQ + q0 + qa + 16] = s1;
    }
    __syncthreads();

    // ---- av phase: thread = (4d x 4q), 8 q-groups over 8 waves ----
    const float* VB = V + ((size_t)b * KK + k0) * DD;
    const int d4 = (t & 63) << 2;
    const int qg = w << 2;                 // 0,4,...,28
    float4 a4[4] = {};
#pragma unroll 4
    for (int k = 0; k < KCH; ++k) {
        float4 v4 = *(const float4*)&VB[(size_t)k * DD + d4];   // coalesced
        float4 p4 = *(float4*)&pT[k][qg];                       // broadcast
        a4[0].x += p4.x * v4.x; a4[0].y += p4.x * v4.y; a4[0].z += p4.x * v4.z; a4[0].w += p4.x * v4.w;
        a4[1].x += p4.y * v4.x; a4[1].y += p4.y * v4.y; a4[1].z += p4.y * v4.z; a4[1].w += p4.y * v4.w;
        a4[2].x += p4.z * v4.x; a4[2].y += p4.z * v4.y; a4[2].z += p4.z * v4.z; a4[2].w += p4.z * v4.w;
        a4[3].x += p4.w * v4.x; a4[3].y += p4.w * v4.y; a4[3].z += p4.w * v4.z; a4[3].w += p4.w * v4.w;
    }
#pragma unroll
    for (int qi = 0; qi < 4; ++qi) {
        int q = q0 + qg + qi;
        *(float4*)&partial[(((size_t)ksb * BB + b) * QQ + q) * DD + d4] = a4[qi];
    }
}

// ---------------------------------------------------------------------------
// K3: mask-aware reduce over the nch(b) live chunks + softmax normalization.
// ---------------------------------------------------------------------------
__global__ __launch_bounds__(256) void av_reduce(const float* __restrict__ partial,
                                                 const float* __restrict__ psum,
                                                 const int* __restrict__ vlen,
                                                 float* __restrict__ out) {
    const int i  = blockIdx.x * 256 + threadIdx.x;   // float4 index, 65536 total
    const int bq = i >> 6;                           // b*QQ + q
    const int b  = bq >> 7;
    const int vl = vlen[b];
    const int nch = (vl == 0) ? KSP : ((vl + KCH - 1) / KCH);

    float S = 0.f;
    for (int ks = 0; ks < nch; ++ks) S += psum[(size_t)ks * (BB * QQ) + bq];

    const float4* p4 = (const float4*)partial;
    const int stride4 = BB * QQ * DD / 4;            // 65536
    float4 s = {0.f, 0.f, 0.f, 0.f};
    for (int ks = 0; ks < nch; ++ks) {
        float4 x = p4[(size_t)ks * stride4 + i];
        s.x += x.x; s.y += x.y; s.z += x.z; s.w += x.w;
    }
    const float inv = 1.0f / S;   // S>0 always: p>=8e-12 unmasked, vl==0 -> p=1
    s.x *= inv; s.y *= inv; s.z *= inv; s.w *= inv;
    ((float4*)out)[i] = s;
}

// ---------------------------------------------------------------------------
extern "C" void kernel_launch(void* const* d_in, const int* in_sizes, int n_in,
                              void* d_out, int out_size, void* d_ws, size_t ws_size,
                              hipStream_t stream) {
    const float* queries = (const float*)d_in[0];   // [B,Q,D]
    const float* keys    = (const float*)d_in[1];   // [B,K,D]
    const float* values  = (const float*)d_in[2];   // [B,K,D]
    const float* W_q     = (const float*)d_in[3];   // [H,D]
    const float* W_k     = (const float*)d_in[4];   // [H,D]
    const float* w_v     = (const float*)d_in[5];   // [H]
    const int*   vlen    = (const int*)d_in[6];     // [B]
    float* out = (float*)d_out;

    float* ws      = (float*)d_ws;
    float* eproj   = ws;                                        // 2359296 floats
    float* psum    = eproj + (size_t)(BB * QQ + BB * KK) * HH;  // KSP*B*Q = 32768
    float* partial = psum + (size_t)KSP * BB * QQ;              // 33.5 MB
    // no aliasing: scoreav reads eproj while writing partial. ~45 MB of ws.

    // Fused Q+K projection (A via LDS, W direct-global), mask-skipped
    proj_kernel<<<dim3((BB * QQ + BB * KK) / 64, HH / 64, 1), 256, 0, stream>>>(
        queries, keys, W_q, W_k, vlen, eproj);

    // Fused score + A*V, h-sliced 8-wave blocks, full 1024-item launch
    scoreav_kernel<<<dim3(KSP * 4 * BB, 1, 1), 512, 0, stream>>>(
        eproj, w_v, vlen, values, partial, psum);

    // Mask-aware reduce + softmax normalization
    av_reduce<<<dim3(BB * QQ * DD / 4 / 256, 1, 1), 256, 0, stream>>>(
        partial, psum, vlen, out);
}

// Round 12
// 143.080 us; speedup vs baseline: 1.1256x; 1.0432x over previous
//
#include <hip/hip_runtime.h>

// Problem constants
#define BB 8
#define QQ 128
#define KK 1024
#define DD 256
#define HH 256

// scoreav split-K: 32 chunks of 32 k
#define KSP 32
#define KCH 32

#define TWO_LOG2E     2.8853900817779268f
#define NEG_TWO_LOG2E -2.8853900817779268f

// ---------------------------------------------------------------------------
// K1: fused Q+K projection with exp2 epilogue — R8 version (measured ~26 us).
// Both A and W staged through LDS; 64x64 tile; 576 blocks, mask-skipped.
// (R11's W-direct-from-global variant regressed ~15 us: 256 VMEM loads per
// block inside the dd-loop expose latency at ~2 blocks/CU. Reverted.)
// ---------------------------------------------------------------------------
__global__ __launch_bounds__(256) void proj_kernel(const float* __restrict__ queries,
                                                   const float* __restrict__ keys,
                                                   const float* __restrict__ Wq,
                                                   const float* __restrict__ Wk,
                                                   const int* __restrict__ vlen,
                                                   float* __restrict__ eproj) {
    const int r0 = blockIdx.x * 64;
    const bool isQ = (r0 < BB * QQ);
    if (!isQ) {
        const int kb = (r0 - BB * QQ) >> 6;
        const int b  = kb >> 4;
        const int k0 = (kb & 15) << 6;
        if (k0 >= vlen[b]) return;               // fully masked (vl==0 too)
    }

    __shared__ float As[64][68];  // pad 68: <=2-way banks (free)
    __shared__ float Ws[64][68];
    const int t  = threadIdx.x;
    const int tr = t & 15;
    const int th = t >> 4;
    const int h0 = blockIdx.y * 64;
    const float* A = isQ ? (queries + (size_t)r0 * DD)
                         : (keys + (size_t)(r0 - BB * QQ) * DD);
    const float* W = isQ ? Wq : Wk;

    float acc[4][4] = {};

    for (int dc = 0; dc < DD; dc += 64) {
#pragma unroll
        for (int i = 0; i < 4; ++i) {
            int fi  = t + 256 * i;
            int row = fi >> 4;
            int c4  = (fi & 15) << 2;
            *(float4*)&As[row][c4] = *(const float4*)&A[(size_t)row * DD + dc + c4];
            *(float4*)&Ws[row][c4] = *(const float4*)&W[(size_t)(h0 + row) * DD + dc + c4];
        }
        __syncthreads();
#pragma unroll 4
        for (int dd = 0; dd < 64; dd += 4) {
            float4 a4[4], w4[4];
#pragma unroll
            for (int i = 0; i < 4; ++i) a4[i] = *(float4*)&As[tr + 16 * i][dd];
#pragma unroll
            for (int i = 0; i < 4; ++i) w4[i] = *(float4*)&Ws[th + 16 * i][dd];
#pragma unroll
            for (int ri = 0; ri < 4; ++ri)
#pragma unroll
                for (int hi = 0; hi < 4; ++hi) {
                    acc[ri][hi] += a4[ri].x * w4[hi].x + a4[ri].y * w4[hi].y +
                                   a4[ri].z * w4[hi].z + a4[ri].w * w4[hi].w;
                }
        }
        __syncthreads();
    }
#pragma unroll
    for (int ri = 0; ri < 4; ++ri)
#pragma unroll
        for (int hi = 0; hi < 4; ++hi) {
            eproj[(size_t)(r0 + tr + 16 * ri) * HH + h0 + th + 16 * hi] =
                __builtin_amdgcn_exp2f(TWO_LOG2E * acc[ri][hi]);
        }
}

// ---------------------------------------------------------------------------
// K2: FUSED score + A*V v3 — h-sliced 8 waves, one-shot staging (R11,
// unchanged). 512 threads; wave w owns h in [32w, 32w+32); thread = 4q x 4k.
// q+k rows staged ONCE (64 KB, coalesced), zero barriers in the h-loop,
// conflict-free fragment reads (stride 260 = 4 mod 32). Occupancy is
// VGPR-bound (128 VGPR -> 4 waves/SIMD) — LDS is not the limiter.
// ---------------------------------------------------------------------------
__global__ __launch_bounds__(512, 4) void scoreav_kernel(const float* __restrict__ eproj,
                                                         const float* __restrict__ wv,
                                                         const int* __restrict__ vlen,
                                                         const float* __restrict__ V,
                                                         float* __restrict__ partial,
                                                         float* __restrict__ psum) {
    // ---- work-item compaction (uniform scalar scan) ----
    int id = blockIdx.x;
    int b = 0;
    bool found = false;
#pragma unroll
    for (int bb = 0; bb < BB; ++bb) {
        if (!found) {
            int v = vlen[bb];
            int cnt = ((v == 0) ? KSP : ((v + KCH - 1) / KCH)) * 4;
            if (id < cnt) { b = bb; found = true; }
            else id -= cnt;
        }
    }
    if (!found) return;
    const int ksb = id >> 2;
    const int q0  = (id & 3) * 32;
    const int k0  = ksb * KCH;
    const int vl  = vlen[b];

    __shared__ float st[2][32][260];   // [0]=q rows, [1]=k rows; all 256 h. 66.6 KB
    __shared__ float pT[KCH][36];      // [k][q]
    float* red = &st[0][0][0];         // alias: red[w*1056 + q*33 + k] (33.8 KB)

    const int t = threadIdx.x;
    const int w = t >> 6;              // wave 0..7
    const int l = t & 63;
    const int ql = l & 7;              // q rows {ql + 8i}
    const int kl = l >> 3;             // k rows {kl + 8j}

    float acc[4][4] = {};

    if (vl > 0) {
        // stage q (32 rows) + k (32 rows) x 256 h: 4096 f4, 8 per thread;
        // each wave reads one contiguous 1 KB row per load (fully coalesced).
#pragma unroll
        for (int i = 0; i < 8; ++i) {
            int fi  = t + 512 * i;             // 0..4095
            int row = fi >> 6;                 // 0..63
            int c4  = (fi & 63) << 2;          // 0..252
            size_t gr = (row < 32) ? (size_t)(b * QQ + q0 + row)
                                   : (size_t)(BB * QQ + b * KK + k0 + row - 32);
            *(float4*)&st[row >> 5][row & 31][c4] =
                *(const float4*)&eproj[gr * HH + c4];
        }
        __syncthreads();

        const int hw = 32 * w;                 // wave's h window
#pragma unroll
        for (int hh = 0; hh < 32; hh += 4) {
            const float4 w4 = *(const float4*)&wv[hw + hh];   // wave-uniform
            const float* wa = (const float*)&w4;
            float4 q4[4], k4[4];
#pragma unroll
            for (int i = 0; i < 4; ++i) q4[i] = *(float4*)&st[0][ql + 8 * i][hw + hh];
#pragma unroll
            for (int j = 0; j < 4; ++j) k4[j] = *(float4*)&st[1][kl + 8 * j][hw + hh];
#pragma unroll
            for (int i = 0; i < 4; ++i) {
                const float* qa = (const float*)&q4[i];
#pragma unroll
                for (int j = 0; j < 4; ++j) {
                    const float* ka = (const float*)&k4[j];
#pragma unroll
                    for (int c = 0; c < 4; ++c) {
                        float d = __builtin_fmaf(qa[c], ka[c], 1.0f);
                        acc[i][j] += wa[c] * __builtin_amdgcn_rcpf(d);
                    }
                }
            }
        }
        __syncthreads();   // staging dead; red may now overwrite it

        // wave-partial accs -> red
#pragma unroll
        for (int i = 0; i < 4; ++i)
#pragma unroll
            for (int j = 0; j < 4; ++j)
                red[w * 1056 + (ql + 8 * i) * 33 + (kl + 8 * j)] = acc[i][j];
    }
    __syncthreads();

    // ---- combine across waves, masked exp2, pT + psum ----
    float pvv[2];
#pragma unroll
    for (int u = 0; u < 2; ++u) {
        int n = t + 512 * u;               // 0..1023
        int q = n >> 5, k = n & 31;
        float s = 0.f;
        if (vl > 0) {
#pragma unroll
            for (int ww = 0; ww < 8; ++ww) s += red[ww * 1056 + q * 33 + k];
        }
        int kg = k0 + k;
        float pv;
        if (vl == 0) pv = 1.0f;            // uniform row (ref behavior)
        else pv = (kg < vl) ? __builtin_amdgcn_exp2f(NEG_TWO_LOG2E * s) : 0.0f;
        pT[k][q] = pv;
        pvv[u] = pv;
    }
    // psum: lanes 0-31 / 32-63 of each wave share a q; reduce within halves
    float s0 = pvv[0], s1 = pvv[1];
#pragma unroll
    for (int off = 1; off < 32; off <<= 1) {
        s0 += __shfl_xor(s0, off);
        s1 += __shfl_xor(s1, off);
    }
    if ((l & 31) == 0) {
        int qa = 2 * w + (l >> 5);         // q for u=0; u=1 is qa+16
        psum[((size_t)ksb * BB + b) * QQ + q0 + qa]      = s0;
        psum[((size_t)ksb * BB + b) * QQ + q0 + qa + 16] = s1;
    }
    __syncthreads();

    // ---- av phase: thread = (4d x 4q), 8 q-groups over 8 waves ----
    const float* VB = V + ((size_t)b * KK + k0) * DD;
    const int d4 = (t & 63) << 2;
    const int qg = w << 2;                 // 0,4,...,28
    float4 a4[4] = {};
#pragma unroll 4
    for (int k = 0; k < KCH; ++k) {
        float4 v4 = *(const float4*)&VB[(size_t)k * DD + d4];   // coalesced
        float4 p4 = *(float4*)&pT[k][qg];                       // broadcast
        a4[0].x += p4.x * v4.x; a4[0].y += p4.x * v4.y; a4[0].z += p4.x * v4.z; a4[0].w += p4.x * v4.w;
        a4[1].x += p4.y * v4.x; a4[1].y += p4.y * v4.y; a4[1].z += p4.y * v4.z; a4[1].w += p4.y * v4.w;
        a4[2].x += p4.z * v4.x; a4[2].y += p4.z * v4.y; a4[2].z += p4.z * v4.z; a4[2].w += p4.z * v4.w;
        a4[3].x += p4.w * v4.x; a4[3].y += p4.w * v4.y; a4[3].z += p4.w * v4.z; a4[3].w += p4.w * v4.w;
    }
#pragma unroll
    for (int qi = 0; qi < 4; ++qi) {
        int q = q0 + qg + qi;
        *(float4*)&partial[(((size_t)ksb * BB + b) * QQ + q) * DD + d4] = a4[qi];
    }
}

// ---------------------------------------------------------------------------
// K3: mask-aware reduce over the nch(b) live chunks + softmax normalization.
// ---------------------------------------------------------------------------
__global__ __launch_bounds__(256) void av_reduce(const float* __restrict__ partial,
                                                 const float* __restrict__ psum,
                                                 const int* __restrict__ vlen,
                                                 float* __restrict__ out) {
    const int i  = blockIdx.x * 256 + threadIdx.x;   // float4 index, 65536 total
    const int bq = i >> 6;                           // b*QQ + q
    const int b  = bq >> 7;
    const int vl = vlen[b];
    const int nch = (vl == 0) ? KSP : ((vl + KCH - 1) / KCH);

    float S = 0.f;
    for (int ks = 0; ks < nch; ++ks) S += psum[(size_t)ks * (BB * QQ) + bq];

    const float4* p4 = (const float4*)partial;
    const int stride4 = BB * QQ * DD / 4;            // 65536
    float4 s = {0.f, 0.f, 0.f, 0.f};
    for (int ks = 0; ks < nch; ++ks) {
        float4 x = p4[(size_t)ks * stride4 + i];
        s.x += x.x; s.y += x.y; s.z += x.z; s.w += x.w;
    }
    const float inv = 1.0f / S;   // S>0 always: p>=8e-12 unmasked, vl==0 -> p=1
    s.x *= inv; s.y *= inv; s.z *= inv; s.w *= inv;
    ((float4*)out)[i] = s;
}

// ---------------------------------------------------------------------------
extern "C" void kernel_launch(void* const* d_in, const int* in_sizes, int n_in,
                              void* d_out, int out_size, void* d_ws, size_t ws_size,
                              hipStream_t stream) {
    const float* queries = (const float*)d_in[0];   // [B,Q,D]
    const float* keys    = (const float*)d_in[1];   // [B,K,D]
    const float* values  = (const float*)d_in[2];   // [B,K,D]
    const float* W_q     = (const float*)d_in[3];   // [H,D]
    const float* W_k     = (const float*)d_in[4];   // [H,D]
    const float* w_v     = (const float*)d_in[5];   // [H]
    const int*   vlen    = (const int*)d_in[6];     // [B]
    float* out = (float*)d_out;

    float* ws      = (float*)d_ws;
    float* eproj   = ws;                                        // 2359296 floats
    float* psum    = eproj + (size_t)(BB * QQ + BB * KK) * HH;  // KSP*B*Q = 32768
    float* partial = psum + (size_t)KSP * BB * QQ;              // 33.5 MB
    // no aliasing: scoreav reads eproj while writing partial. ~45 MB of ws.

    // Fused Q+K projection with exp2 epilogue (R8 version), mask-skipped
    proj_kernel<<<dim3((BB * QQ + BB * KK) / 64, HH / 64, 1), 256, 0, stream>>>(
        queries, keys, W_q, W_k, vlen, eproj);

    // Fused score + A*V, h-sliced 8-wave blocks, full 1024-item launch
    scoreav_kernel<<<dim3(KSP * 4 * BB, 1, 1), 512, 0, stream>>>(
        eproj, w_v, vlen, values, partial, psum);

    // Mask-aware reduce + softmax normalization
    av_reduce<<<dim3(BB * QQ * DD / 4 / 256, 1, 1), 256, 0, stream>>>(
        partial, psum, vlen, out);
}

// Round 13
// 142.721 us; speedup vs baseline: 1.1285x; 1.0025x over previous
//
#include <hip/hip_runtime.h>

// Problem constants
#define BB 8
#define QQ 128
#define KK 1024
#define DD 256
#define HH 256

// scoreav split-K: 32 chunks of 32 k
#define KSP 32
#define KCH 32

// proj D-split
#define RTOT (BB * QQ + BB * KK)          // 9216 rows
#define PSTRIDE ((size_t)RTOT * HH)       // floats per D-half buffer

#define TWO_LOG2E     2.8853900817779268f
#define NEG_TWO_LOG2E -2.8853900817779268f

// ---------------------------------------------------------------------------
// K1: Q+K projection, D-SPLIT x2. Block (r-tile 64, h-tile 64, z in {0,1});
// z accumulates d in [128z, 128z+128) and writes pp[z] = 2log2e * acc_half
// (no exp2 here; scoreav staging computes exp2(pp0+pp1) — identical value).
// Why: after mask-skip the unsplit grid had ~320 live blocks = 1.25/CU and
// sat latency-bound at 26 us vs a 13 us LDS floor (stuck since R4). Split:
// ~650 live = 2.55/CU, half work per block. Same 0.125 b128/MAC ratio.
// MASK SKIP: key blocks fully >= vl[b] -> early out (coverage still >=
// scoreav's reads; 0xAA poison, if ever touched, is ~-3e-13 -> harmless).
// ---------------------------------------------------------------------------
__global__ __launch_bounds__(256) void proj_kernel(const float* __restrict__ queries,
                                                   const float* __restrict__ keys,
                                                   const float* __restrict__ Wq,
                                                   const float* __restrict__ Wk,
                                                   const int* __restrict__ vlen,
                                                   float* __restrict__ pp) {
    const int r0 = blockIdx.x * 64;
    const bool isQ = (r0 < BB * QQ);
    if (!isQ) {
        const int kb = (r0 - BB * QQ) >> 6;
        const int b  = kb >> 4;
        const int k0 = (kb & 15) << 6;
        if (k0 >= vlen[b]) return;               // fully masked (vl==0 too)
    }

    __shared__ float As[64][68];  // pad 68: <=2-way banks (free)
    __shared__ float Ws[64][68];
    const int t  = threadIdx.x;
    const int tr = t & 15;
    const int th = t >> 4;
    const int h0 = blockIdx.y * 64;
    const int dc0 = blockIdx.z * 128;            // D-half base
    const float* A = isQ ? (queries + (size_t)r0 * DD)
                         : (keys + (size_t)(r0 - BB * QQ) * DD);
    const float* W = isQ ? Wq : Wk;

    float acc[4][4] = {};

    for (int dc = dc0; dc < dc0 + 128; dc += 64) {
#pragma unroll
        for (int i = 0; i < 4; ++i) {
            int fi  = t + 256 * i;
            int row = fi >> 4;
            int c4  = (fi & 15) << 2;
            *(float4*)&As[row][c4] = *(const float4*)&A[(size_t)row * DD + dc + c4];
            *(float4*)&Ws[row][c4] = *(const float4*)&W[(size_t)(h0 + row) * DD + dc + c4];
        }
        __syncthreads();
#pragma unroll 4
        for (int dd = 0; dd < 64; dd += 4) {
            float4 a4[4], w4[4];
#pragma unroll
            for (int i = 0; i < 4; ++i) a4[i] = *(float4*)&As[tr + 16 * i][dd];
#pragma unroll
            for (int i = 0; i < 4; ++i) w4[i] = *(float4*)&Ws[th + 16 * i][dd];
#pragma unroll
            for (int ri = 0; ri < 4; ++ri)
#pragma unroll
                for (int hi = 0; hi < 4; ++hi) {
                    acc[ri][hi] += a4[ri].x * w4[hi].x + a4[ri].y * w4[hi].y +
                                   a4[ri].z * w4[hi].z + a4[ri].w * w4[hi].w;
                }
        }
        __syncthreads();
    }

    float* outp = pp + (size_t)blockIdx.z * PSTRIDE;
#pragma unroll
    for (int ri = 0; ri < 4; ++ri)
#pragma unroll
        for (int hi = 0; hi < 4; ++hi) {
            outp[(size_t)(r0 + tr + 16 * ri) * HH + h0 + th + 16 * hi] =
                TWO_LOG2E * acc[ri][hi];
        }
}

// ---------------------------------------------------------------------------
// K2: FUSED score + A*V v3 — h-sliced 8 waves, one-shot staging. Staging now
// combines the two proj D-halves: st = exp2(pp0 + pp1) (16 f4 loads + 4
// exp2-f4 per thread; ~0.5 us exp2 total, ~2 us extra L2 traffic).
// Otherwise identical to R12: zero barriers in the h-loop, conflict-free
// fragment reads (stride 260 = 4 mod 32), VGPR-bound 4 waves/SIMD.
// ---------------------------------------------------------------------------
__global__ __launch_bounds__(512, 4) void scoreav_kernel(const float* __restrict__ pp,
                                                         const float* __restrict__ wv,
                                                         const int* __restrict__ vlen,
                                                         const float* __restrict__ V,
                                                         float* __restrict__ partial,
                                                         float* __restrict__ psum) {
    // ---- work-item compaction (uniform scalar scan) ----
    int id = blockIdx.x;
    int b = 0;
    bool found = false;
#pragma unroll
    for (int bb = 0; bb < BB; ++bb) {
        if (!found) {
            int v = vlen[bb];
            int cnt = ((v == 0) ? KSP : ((v + KCH - 1) / KCH)) * 4;
            if (id < cnt) { b = bb; found = true; }
            else id -= cnt;
        }
    }
    if (!found) return;
    const int ksb = id >> 2;
    const int q0  = (id & 3) * 32;
    const int k0  = ksb * KCH;
    const int vl  = vlen[b];

    __shared__ float st[2][32][260];   // [0]=q rows, [1]=k rows; all 256 h. 66.6 KB
    __shared__ float pT[KCH][36];      // [k][q]
    float* red = &st[0][0][0];         // alias: red[w*1056 + q*33 + k] (33.8 KB)

    const int t = threadIdx.x;
    const int w = t >> 6;              // wave 0..7
    const int l = t & 63;
    const int ql = l & 7;              // q rows {ql + 8i}
    const int kl = l >> 3;             // k rows {kl + 8j}

    float acc[4][4] = {};

    if (vl > 0) {
        // stage q (32 rows) + k (32 rows) x 256 h: 4096 f4, 8 per thread;
        // combine D-halves + exp2 inline. Coalesced 1 KB/wave row reads.
#pragma unroll
        for (int i = 0; i < 8; ++i) {
            int fi  = t + 512 * i;             // 0..4095
            int row = fi >> 6;                 // 0..63
            int c4  = (fi & 63) << 2;          // 0..252
            size_t gr = (row < 32) ? (size_t)(b * QQ + q0 + row)
                                   : (size_t)(BB * QQ + b * KK + k0 + row - 32);
            const float* base = pp + gr * HH + c4;
            float4 v0 = *(const float4*)base;
            float4 v1 = *(const float4*)(base + PSTRIDE);
            float4 s;
            s.x = __builtin_amdgcn_exp2f(v0.x + v1.x);
            s.y = __builtin_amdgcn_exp2f(v0.y + v1.y);
            s.z = __builtin_amdgcn_exp2f(v0.z + v1.z);
            s.w = __builtin_amdgcn_exp2f(v0.w + v1.w);
            *(float4*)&st[row >> 5][row & 31][c4] = s;
        }
        __syncthreads();

        const int hw = 32 * w;                 // wave's h window
#pragma unroll
        for (int hh = 0; hh < 32; hh += 4) {
            const float4 w4 = *(const float4*)&wv[hw + hh];   // wave-uniform
            const float* wa = (const float*)&w4;
            float4 q4[4], k4[4];
#pragma unroll
            for (int i = 0; i < 4; ++i) q4[i] = *(float4*)&st[0][ql + 8 * i][hw + hh];
#pragma unroll
            for (int j = 0; j < 4; ++j) k4[j] = *(float4*)&st[1][kl + 8 * j][hw + hh];
#pragma unroll
            for (int i = 0; i < 4; ++i) {
                const float* qa = (const float*)&q4[i];
#pragma unroll
                for (int j = 0; j < 4; ++j) {
                    const float* ka = (const float*)&k4[j];
#pragma unroll
                    for (int c = 0; c < 4; ++c) {
                        float d = __builtin_fmaf(qa[c], ka[c], 1.0f);
                        acc[i][j] += wa[c] * __builtin_amdgcn_rcpf(d);
                    }
                }
            }
        }
        __syncthreads();   // staging dead; red may now overwrite it

        // wave-partial accs -> red
#pragma unroll
        for (int i = 0; i < 4; ++i)
#pragma unroll
            for (int j = 0; j < 4; ++j)
                red[w * 1056 + (ql + 8 * i) * 33 + (kl + 8 * j)] = acc[i][j];
    }
    __syncthreads();

    // ---- combine across waves, masked exp2, pT + psum ----
    float pvv[2];
#pragma unroll
    for (int u = 0; u < 2; ++u) {
        int n = t + 512 * u;               // 0..1023
        int q = n >> 5, k = n & 31;
        float s = 0.f;
        if (vl > 0) {
#pragma unroll
            for (int ww = 0; ww < 8; ++ww) s += red[ww * 1056 + q * 33 + k];
        }
        int kg = k0 + k;
        float pv;
        if (vl == 0) pv = 1.0f;            // uniform row (ref behavior)
        else pv = (kg < vl) ? __builtin_amdgcn_exp2f(NEG_TWO_LOG2E * s) : 0.0f;
        pT[k][q] = pv;
        pvv[u] = pv;
    }
    // psum: lanes 0-31 / 32-63 of each wave share a q; reduce within halves
    float s0 = pvv[0], s1 = pvv[1];
#pragma unroll
    for (int off = 1; off < 32; off <<= 1) {
        s0 += __shfl_xor(s0, off);
        s1 += __shfl_xor(s1, off);
    }
    if ((l & 31) == 0) {
        int qa = 2 * w + (l >> 5);         // q for u=0; u=1 is qa+16
        psum[((size_t)ksb * BB + b) * QQ + q0 + qa]      = s0;
        psum[((size_t)ksb * BB + b) * QQ + q0 + qa + 16] = s1;
    }
    __syncthreads();

    // ---- av phase: thread = (4d x 4q), 8 q-groups over 8 waves ----
    const float* VB = V + ((size_t)b * KK + k0) * DD;
    const int d4 = (t & 63) << 2;
    const int qg = w << 2;                 // 0,4,...,28
    float4 a4[4] = {};
#pragma unroll 4
    for (int k = 0; k < KCH; ++k) {
        float4 v4 = *(const float4*)&VB[(size_t)k * DD + d4];   // coalesced
        float4 p4 = *(float4*)&pT[k][qg];                       // broadcast
        a4[0].x += p4.x * v4.x; a4[0].y += p4.x * v4.y; a4[0].z += p4.x * v4.z; a4[0].w += p4.x * v4.w;
        a4[1].x += p4.y * v4.x; a4[1].y += p4.y * v4.y; a4[1].z += p4.y * v4.z; a4[1].w += p4.y * v4.w;
        a4[2].x += p4.z * v4.x; a4[2].y += p4.z * v4.y; a4[2].z += p4.z * v4.z; a4[2].w += p4.z * v4.w;
        a4[3].x += p4.w * v4.x; a4[3].y += p4.w * v4.y; a4[3].z += p4.w * v4.z; a4[3].w += p4.w * v4.w;
    }
#pragma unroll
    for (int qi = 0; qi < 4; ++qi) {
        int q = q0 + qg + qi;
        *(float4*)&partial[(((size_t)ksb * BB + b) * QQ + q) * DD + d4] = a4[qi];
    }
}

// ---------------------------------------------------------------------------
// K3: mask-aware reduce over the nch(b) live chunks + softmax normalization.
// ---------------------------------------------------------------------------
__global__ __launch_bounds__(256) void av_reduce(const float* __restrict__ partial,
                                                 const float* __restrict__ psum,
                                                 const int* __restrict__ vlen,
                                                 float* __restrict__ out) {
    const int i  = blockIdx.x * 256 + threadIdx.x;   // float4 index, 65536 total
    const int bq = i >> 6;                           // b*QQ + q
    const int b  = bq >> 7;
    const int vl = vlen[b];
    const int nch = (vl == 0) ? KSP : ((vl + KCH - 1) / KCH);

    float S = 0.f;
    for (int ks = 0; ks < nch; ++ks) S += psum[(size_t)ks * (BB * QQ) + bq];

    const float4* p4 = (const float4*)partial;
    const int stride4 = BB * QQ * DD / 4;            // 65536
    float4 s = {0.f, 0.f, 0.f, 0.f};
    for (int ks = 0; ks < nch; ++ks) {
        float4 x = p4[(size_t)ks * stride4 + i];
        s.x += x.x; s.y += x.y; s.z += x.z; s.w += x.w;
    }
    const float inv = 1.0f / S;   // S>0 always: p>=8e-12 unmasked, vl==0 -> p=1
    s.x *= inv; s.y *= inv; s.z *= inv; s.w *= inv;
    ((float4*)out)[i] = s;
}

// ---------------------------------------------------------------------------
extern "C" void kernel_launch(void* const* d_in, const int* in_sizes, int n_in,
                              void* d_out, int out_size, void* d_ws, size_t ws_size,
                              hipStream_t stream) {
    const float* queries = (const float*)d_in[0];   // [B,Q,D]
    const float* keys    = (const float*)d_in[1];   // [B,K,D]
    const float* values  = (const float*)d_in[2];   // [B,K,D]
    const float* W_q     = (const float*)d_in[3];   // [H,D]
    const float* W_k     = (const float*)d_in[4];   // [H,D]
    const float* w_v     = (const float*)d_in[5];   // [H]
    const int*   vlen    = (const int*)d_in[6];     // [B]
    float* out = (float*)d_out;

    float* ws      = (float*)d_ws;
    float* pp      = ws;                                  // 2*PSTRIDE = 18.9 MB
    float* psum    = pp + 2 * PSTRIDE;                    // KSP*B*Q = 32768
    float* partial = psum + (size_t)KSP * BB * QQ;        // 33.5 MB
    // no aliasing: scoreav reads pp while writing partial. ~53 MB of ws.

    // D-split Q+K projection (pp halves, no exp2), mask-skipped
    proj_kernel<<<dim3(RTOT / 64, HH / 64, 2), 256, 0, stream>>>(
        queries, keys, W_q, W_k, vlen, pp);

    // Fused score + A*V, h-sliced 8-wave blocks, D-half combine in staging
    scoreav_kernel<<<dim3(KSP * 4 * BB, 1, 1), 512, 0, stream>>>(
        pp, w_v, vlen, values, partial, psum);

    // Mask-aware reduce + softmax normalization
    av_reduce<<<dim3(BB * QQ * DD / 4 / 256, 1, 1), 256, 0, stream>>>(
        partial, psum, vlen, out);
}